// Round 7
// baseline (3411.726 us; speedup 1.0000x reference)
//
#include <hip/hip_runtime.h>

typedef _Float16 half8  __attribute__((ext_vector_type(8)));
typedef _Float16 half4v __attribute__((ext_vector_type(4)));
typedef float    floatx4 __attribute__((ext_vector_type(4)));
typedef unsigned long long u64;

#define B_ 32
#define S_ 512
#define I_ 1024
#define H_ 1024
#define M_TOT (B_ * S_)   // 16384

// ---------------------------------------------------------------------------
// fp32 -> fp16 conversion (vectorized, grid-stride), n multiple of 4
// ---------------------------------------------------------------------------
__global__ void cvt_f32_f16(const float* __restrict__ src, _Float16* __restrict__ dst, long n) {
  long i = ((long)blockIdx.x * blockDim.x + threadIdx.x) * 4;
  const long stride = (long)gridDim.x * blockDim.x * 4;
  for (; i < n; i += stride) {
    floatx4 v = *(const floatx4*)(src + i);
    half4v h = {(_Float16)v[0], (_Float16)v[1], (_Float16)v[2], (_Float16)v[3]};
    *(half4v*)(dst + i) = h;
  }
}

__global__ void bias_sum_kernel(const float* __restrict__ bihf, const float* __restrict__ bhhf,
                                const float* __restrict__ bihb, const float* __restrict__ bhhb,
                                float* __restrict__ bias, unsigned int* __restrict__ counter) {
  int i = blockIdx.x * blockDim.x + threadIdx.x;
  if (i == 0) {
    __hip_atomic_store(counter,      0u, __ATOMIC_RELAXED, __HIP_MEMORY_SCOPE_AGENT); // prologue
    __hip_atomic_store(counter + 32, 0u, __ATOMIC_RELAXED, __HIP_MEMORY_SCOPE_AGENT); // fwd
    __hip_atomic_store(counter + 64, 0u, __ATOMIC_RELAXED, __HIP_MEMORY_SCOPE_AGENT); // bwd
  }
  if (i < H_) {
    bias[i]      = bihf[i] + bhhf[i];
    bias[H_ + i] = bihb[i] + bhhb[i];
  }
}

// ---------------------------------------------------------------------------
// GEMM: xp[dir][m][n] = sum_k x16[m][k] * W16[dir][n][k] + bias[dir][n]
// stored into out[m*2048 + dir*1024 + n] (xp lives in d_out; scan updates it
// in place).
// ---------------------------------------------------------------------------
__global__ void __launch_bounds__(256) gemm_xp_kernel(
    const _Float16* __restrict__ A,
    const _Float16* __restrict__ W,
    const float*    __restrict__ bias,
    float*          __restrict__ out)
{
  __shared__ _Float16 alds[128 * 32];
  __shared__ _Float16 blds[128 * 32];

  const int dir = blockIdx.z;
  const int m0  = blockIdx.y * 128;
  const int n0  = blockIdx.x * 128;
  const int tid  = threadIdx.x;
  const int lane = tid & 63;
  const int wv   = tid >> 6;
  const int wm   = wv >> 1, wn = wv & 1;
  const int lrow = lane & 15;
  const int lkg  = lane >> 4;

  const _Float16* Wd = W + (long)dir * H_ * I_;

  floatx4 acc[4][4] = {};

  const int srow = tid >> 1;
  const int sseg = tid & 1;

  for (int kt = 0; kt < 32; ++kt) {
    __syncthreads();
    {
      const _Float16* srcA = A  + (long)(m0 + srow) * I_ + kt * 32 + sseg * 16;
      const _Float16* srcB = Wd + (long)(n0 + srow) * I_ + kt * 32 + sseg * 16;
      half8 a0 = *(const half8*)(srcA);
      half8 a1 = *(const half8*)(srcA + 8);
      half8 b0 = *(const half8*)(srcB);
      half8 b1 = *(const half8*)(srcB + 8);
      const int sw = (srow & 7) << 4;
      const int base = srow * 64 + sseg * 32;
      *(half8*)((char*)alds + ((base     ) ^ sw)) = a0;
      *(half8*)((char*)alds + ((base + 16) ^ sw)) = a1;
      *(half8*)((char*)blds + ((base     ) ^ sw)) = b0;
      *(half8*)((char*)blds + ((base + 16) ^ sw)) = b1;
    }
    __syncthreads();

    half8 af[4], bf[4];
#pragma unroll
    for (int mt = 0; mt < 4; ++mt) {
      int r = wm * 64 + mt * 16 + lrow;
      int byte = (r * 64 + lkg * 16) ^ ((r & 7) << 4);
      af[mt] = *(const half8*)((const char*)alds + byte);
    }
#pragma unroll
    for (int ntt = 0; ntt < 4; ++ntt) {
      int r = wn * 64 + ntt * 16 + lrow;
      int byte = (r * 64 + lkg * 16) ^ ((r & 7) << 4);
      bf[ntt] = *(const half8*)((const char*)blds + byte);
    }
#pragma unroll
    for (int mt = 0; mt < 4; ++mt)
#pragma unroll
      for (int ntt = 0; ntt < 4; ++ntt)
        acc[mt][ntt] = __builtin_amdgcn_mfma_f32_16x16x32_f16(af[mt], bf[ntt], acc[mt][ntt], 0, 0, 0);
  }

#pragma unroll
  for (int mt = 0; mt < 4; ++mt) {
    int mrow = m0 + wm * 64 + mt * 16 + lkg * 4;
#pragma unroll
    for (int ntt = 0; ntt < 4; ++ntt) {
      int n = n0 + wn * 64 + ntt * 16 + lrow;
      float bv = bias[dir * H_ + n];
#pragma unroll
      for (int v = 0; v < 4; ++v) {
        out[(long)(mrow + v) * (2 * H_) + dir * H_ + n] = acc[mt][ntt][v] + bv;
      }
    }
  }
}

// ---------------------------------------------------------------------------
// Recurrent scan, direction-interleaved edition.
// 64 WGs; WG rb owns rows [rb*16, rb*16+16) of BOTH directions.
// Per iteration t: fwd phase then bwd phase. Each direction's barrier
// (h-store ack + signal propagation + 64-WG arrival) completes while the WG
// computes the OTHER direction's phase. The barrier poll runs on tid 255
// (an idle kh=1 lane) during the phase tail -> zero poll latency at phase
// start. All cross-WG traffic at agent scope (sc1 -> MALL), proven R4/R6.
// Waves = (nt batch-half, kh K-half); kh partials exchanged via LDS.
// ---------------------------------------------------------------------------
__global__ void __launch_bounds__(256, 1) scan_kernel(
    const float* __restrict__ Whh_f,
    const float* __restrict__ Whh_b,
    float*       __restrict__ out,     // [B][S][2H]; holds xp on entry
    _Float16*    __restrict__ hbuf,    // [2 buf][2 dir][B][H] f16
    unsigned int* __restrict__ counter) // [0]=prologue, [32]=fwd, [64]=bwd
{
  __shared__ _Float16 wlds[2 * 16 * 1024];  // 64 KiB [dir][row][k]
  __shared__ floatx4  redlds[128];          // 2 KiB [nt][lane]

  const int rb    = blockIdx.x;   // 0..63
  const int rows0 = rb * 16;
  const int tid   = threadIdx.x;
  unsigned int* ctr_f = counter + 32;
  unsigned int* ctr_b = counter + 64;

  // stage W_hh rows [rows0, rows0+16) for both dirs, swizzled
  for (int idx = tid; idx < 2 * 16 * 128; idx += 256) {
    const int d  = idx >> 11;
    const int r  = (idx >> 7) & 15;
    const int kg = idx & 127;
    const float* W = d ? Whh_b : Whh_f;
    const float* src = W + (long)(rows0 + r) * H_ + kg * 8;
    floatx4 v0 = *(const floatx4*)(src);
    floatx4 v1 = *(const floatx4*)(src + 4);
    half8 h = {(_Float16)v0[0], (_Float16)v0[1], (_Float16)v0[2], (_Float16)v0[3],
               (_Float16)v1[0], (_Float16)v1[1], (_Float16)v1[2], (_Float16)v1[3]};
    const int byte = d * 32768 + ((r * 2048 + kg * 16) ^ ((r & 7) << 4));
    *(half8*)((char*)wlds + byte) = h;
  }

  // zero own h0 slices (both dirs): 2 dirs x 32 b x 4 u64(16 rows) = 256
  {
    const int d  = tid >> 7;
    const int b  = (tid >> 2) & 31;
    const int rg = tid & 3;
    u64* p = (u64*)(hbuf + ((long)(0 * 2 + d) * B_ + b) * H_ + rows0 + rg * 4);
    __hip_atomic_store(p, (u64)0, __ATOMIC_RELAXED, __HIP_MEMORY_SCOPE_AGENT);
  }

  // prologue barrier (all 64 WGs)
  asm volatile("s_waitcnt vmcnt(0)" ::: "memory");
  __syncthreads();
  if (tid == 0) {
    __hip_atomic_fetch_add(counter, 1u, __ATOMIC_RELAXED, __HIP_MEMORY_SCOPE_AGENT);
    while (__hip_atomic_load(counter, __ATOMIC_RELAXED, __HIP_MEMORY_SCOPE_AGENT) < 64u)
      __builtin_amdgcn_s_sleep(1);
  }
  __syncthreads();

  // wave/lane roles
  const int lane = tid & 63;
  const int wv   = tid >> 6;
  const int nt   = wv & 1;          // batch half
  const int kh   = wv >> 1;         // K half
  const int lrow = lane & 15;
  const int lkg  = lane >> 4;       // 0..3
  const int b_idx = nt * 16 + lrow; // batch
  const int kbase = kh * 512;       // K-half start (halves)
  const int r0    = rows0 + lkg * 4;            // kh==0 lanes' 4 output rows
  const int asw   = (lrow & 7) << 4;
  const int abase_f = lrow * 2048 + kbase * 2;          // dir0 row byte base
  const int abase_b = 32768 + lrow * 2048 + kbase * 2;  // dir1 row byte base

  // xp prefetch state (kh==0 only)
  long o_f = 0, o_b = 0;
  floatx4 xp_f = {}, xp_b = {};
  if (kh == 0) {
    o_f = ((long)b_idx * S_ + 0) * (2 * H_) + 0 * H_ + r0;
    o_b = ((long)b_idx * S_ + (S_ - 1)) * (2 * H_) + 1 * H_ + r0;
    xp_f = *(const floatx4*)(out + o_f);
    xp_b = *(const floatx4*)(out + o_b);
  }

#pragma unroll 1
  for (int t = 0; t < S_; ++t) {
    const bool last = (t == S_ - 1);
    const int p = t & 1;

    // ========================= FWD phase =========================
    {
      const _Float16* hp = hbuf + ((long)(p * 2 + 0) * B_ + b_idx) * H_ + kbase + lkg * 8;
      half8 hr[16];
#pragma unroll
      for (int kt = 0; kt < 16; ++kt)
        asm volatile("global_load_dwordx4 %0, %1, off offset:%2 sc1"
                     : "=v"(hr[kt]) : "v"(hp), "i"(kt * 64) : "memory");
      asm volatile("s_waitcnt vmcnt(0)" ::: "memory");
      __builtin_amdgcn_sched_barrier(0);

      floatx4 a0 = {}, a1 = {};
#pragma unroll
      for (int kt = 0; kt < 16; ++kt) {
        const int byte = (abase_f + kt * 64 + lkg * 16) ^ asw;
        half8 a = *(const half8*)((const char*)wlds + byte);
        if (kt & 1) a1 = __builtin_amdgcn_mfma_f32_16x16x32_f16(a, hr[kt], a1, 0, 0, 0);
        else        a0 = __builtin_amdgcn_mfma_f32_16x16x32_f16(a, hr[kt], a0, 0, 0, 0);
      }
      floatx4 accs = a0 + a1;
      if (kh == 1) redlds[nt * 64 + lane] = accs;
      __syncthreads();

      // hidden poll: verify bwd barrier for THIS iteration (idle kh=1 lane)
      if (tid == 255) {
        const unsigned int tgt = 64u * (unsigned)t;
        unsigned int v = __hip_atomic_load(ctr_b, __ATOMIC_RELAXED, __HIP_MEMORY_SCOPE_AGENT);
        while (v < tgt) {
          __builtin_amdgcn_s_sleep(1);
          v = __hip_atomic_load(ctr_b, __ATOMIC_RELAXED, __HIP_MEMORY_SCOPE_AGENT);
        }
      }

      if (kh == 0) {
        floatx4 tot = accs + redlds[nt * 64 + lane];
        floatx4 hv;
#pragma unroll
        for (int v = 0; v < 4; ++v) {
          float z = tot[v] + xp_f[v];
          hv[v] = 1.f - 2.f / (__expf(2.f * z) + 1.f);   // tanh(z)
        }
        *(floatx4*)(out + o_f) = hv;
        if (!last) {
          union { half4v h; u64 u; } hh;
          hh.h = half4v{(_Float16)hv[0], (_Float16)hv[1], (_Float16)hv[2], (_Float16)hv[3]};
          u64* dst = (u64*)(hbuf + ((long)((1 - p) * 2 + 0) * B_ + b_idx) * H_ + r0);
          __hip_atomic_store(dst, hh.u, __ATOMIC_RELAXED, __HIP_MEMORY_SCOPE_AGENT);
        }
      }

      asm volatile("s_waitcnt vmcnt(0)" ::: "memory");
      __syncthreads();
      if (!last) {
        if (tid == 0)
          __hip_atomic_fetch_add(ctr_f, 1u, __ATOMIC_RELAXED, __HIP_MEMORY_SCOPE_AGENT);
        if (kh == 0) {  // xp prefetch after signal: latency hides under bwd phase
          o_f = ((long)b_idx * S_ + (t + 1)) * (2 * H_) + 0 * H_ + r0;
          xp_f = *(const floatx4*)(out + o_f);
        }
      }
    }

    // ========================= BWD phase =========================
    {
      const _Float16* hp = hbuf + ((long)(p * 2 + 1) * B_ + b_idx) * H_ + kbase + lkg * 8;
      half8 hr[16];
#pragma unroll
      for (int kt = 0; kt < 16; ++kt)
        asm volatile("global_load_dwordx4 %0, %1, off offset:%2 sc1"
                     : "=v"(hr[kt]) : "v"(hp), "i"(kt * 64) : "memory");
      asm volatile("s_waitcnt vmcnt(0)" ::: "memory");
      __builtin_amdgcn_sched_barrier(0);

      floatx4 a0 = {}, a1 = {};
#pragma unroll
      for (int kt = 0; kt < 16; ++kt) {
        const int byte = (abase_b + kt * 64 + lkg * 16) ^ asw;
        half8 a = *(const half8*)((const char*)wlds + byte);
        if (kt & 1) a1 = __builtin_amdgcn_mfma_f32_16x16x32_f16(a, hr[kt], a1, 0, 0, 0);
        else        a0 = __builtin_amdgcn_mfma_f32_16x16x32_f16(a, hr[kt], a0, 0, 0, 0);
      }
      floatx4 accs = a0 + a1;
      if (kh == 1) redlds[nt * 64 + lane] = accs;
      __syncthreads();

      // hidden poll: verify fwd barrier for NEXT iteration
      if (tid == 255 && !last) {
        const unsigned int tgt = 64u * (unsigned)(t + 1);
        unsigned int v = __hip_atomic_load(ctr_f, __ATOMIC_RELAXED, __HIP_MEMORY_SCOPE_AGENT);
        while (v < tgt) {
          __builtin_amdgcn_s_sleep(1);
          v = __hip_atomic_load(ctr_f, __ATOMIC_RELAXED, __HIP_MEMORY_SCOPE_AGENT);
        }
      }

      if (kh == 0) {
        floatx4 tot = accs + redlds[nt * 64 + lane];
        floatx4 hv;
#pragma unroll
        for (int v = 0; v < 4; ++v) {
          float z = tot[v] + xp_b[v];
          hv[v] = 1.f - 2.f / (__expf(2.f * z) + 1.f);   // tanh(z)
        }
        *(floatx4*)(out + o_b) = hv;
        if (!last) {
          union { half4v h; u64 u; } hh;
          hh.h = half4v{(_Float16)hv[0], (_Float16)hv[1], (_Float16)hv[2], (_Float16)hv[3]};
          u64* dst = (u64*)(hbuf + ((long)((1 - p) * 2 + 1) * B_ + b_idx) * H_ + r0);
          __hip_atomic_store(dst, hh.u, __ATOMIC_RELAXED, __HIP_MEMORY_SCOPE_AGENT);
        }
      }

      asm volatile("s_waitcnt vmcnt(0)" ::: "memory");
      __syncthreads();
      if (!last) {
        if (tid == 0)
          __hip_atomic_fetch_add(ctr_b, 1u, __ATOMIC_RELAXED, __HIP_MEMORY_SCOPE_AGENT);
        if (kh == 0) {  // xp prefetch: latency hides under next fwd phase
          o_b = ((long)b_idx * S_ + (S_ - 2 - t)) * (2 * H_) + 1 * H_ + r0;
          xp_b = *(const floatx4*)(out + o_b);
        }
      }
    }
  }
}

// ---------------------------------------------------------------------------
extern "C" void kernel_launch(void* const* d_in, const int* in_sizes, int n_in,
                              void* d_out, int out_size, void* d_ws, size_t ws_size,
                              hipStream_t stream) {
  const float* x    = (const float*)d_in[0];
  const float* Wihf = (const float*)d_in[1];
  const float* Whhf = (const float*)d_in[2];
  const float* bihf = (const float*)d_in[3];
  const float* bhhf = (const float*)d_in[4];
  const float* Wihb = (const float*)d_in[5];
  const float* Whhb = (const float*)d_in[6];
  const float* bihb = (const float*)d_in[7];
  const float* bhhb = (const float*)d_in[8];
  float* out = (float*)d_out;

  // workspace layout
  char* ws = (char*)d_ws;
  _Float16*     x16  = (_Float16*)ws;                          // 32 MiB
  _Float16*     w16  = (_Float16*)(ws + 33554432u);            // 4 MiB
  float*        bias = (float*)   (ws + 33554432u + 4194304u); // 8 KiB
  _Float16*     hbuf = (_Float16*)(ws + 37756928u);            // 256 KiB
  unsigned int* counter = (unsigned int*)(ws + 38019072u);     // 3 ctrs, 128B apart

  cvt_f32_f16<<<4096, 256, 0, stream>>>(x, x16, (long)M_TOT * I_);
  cvt_f32_f16<<<1024, 256, 0, stream>>>(Wihf, w16, (long)H_ * I_);
  cvt_f32_f16<<<1024, 256, 0, stream>>>(Wihb, w16 + (long)H_ * I_, (long)H_ * I_);
  bias_sum_kernel<<<4, 256, 0, stream>>>(bihf, bhhf, bihb, bhhb, bias, counter);

  dim3 g(H_ / 128, M_TOT / 128, 2);
  gemm_xp_kernel<<<g, 256, 0, stream>>>(x16, w16, bias, out);

  void* args[] = {(void*)&Whhf, (void*)&Whhb, (void*)&out, (void*)&hbuf, (void*)&counter};
  (void)hipLaunchCooperativeKernel((void*)scan_kernel, dim3(64), dim3(256),
                                   args, 0, stream);
}

// Round 8
// 3110.419 us; speedup vs baseline: 1.0969x; 1.0969x over previous
//
#include <hip/hip_runtime.h>

typedef _Float16 half8  __attribute__((ext_vector_type(8)));
typedef _Float16 half4v __attribute__((ext_vector_type(4)));
typedef float    floatx4 __attribute__((ext_vector_type(4)));
typedef unsigned long long u64;

#define B_ 32
#define S_ 512
#define I_ 1024
#define H_ 1024
#define M_TOT (B_ * S_)   // 16384

// ---------------------------------------------------------------------------
// fp32 -> fp16 conversion (vectorized, grid-stride), n multiple of 4
// ---------------------------------------------------------------------------
__global__ void cvt_f32_f16(const float* __restrict__ src, _Float16* __restrict__ dst, long n) {
  long i = ((long)blockIdx.x * blockDim.x + threadIdx.x) * 4;
  const long stride = (long)gridDim.x * blockDim.x * 4;
  for (; i < n; i += stride) {
    floatx4 v = *(const floatx4*)(src + i);
    half4v h = {(_Float16)v[0], (_Float16)v[1], (_Float16)v[2], (_Float16)v[3]};
    *(half4v*)(dst + i) = h;
  }
}

__global__ void bias_sum_kernel(const float* __restrict__ bihf, const float* __restrict__ bhhf,
                                const float* __restrict__ bihb, const float* __restrict__ bhhb,
                                float* __restrict__ bias, unsigned int* __restrict__ flags) {
  int i = blockIdx.x * blockDim.x + threadIdx.x;
  if (i < 256) {  // zero all publication flags (2 dirs x 128) each launch
    __hip_atomic_store(flags + i, 0u, __ATOMIC_RELAXED, __HIP_MEMORY_SCOPE_AGENT);
  }
  if (i < H_) {
    bias[i]      = bihf[i] + bhhf[i];
    bias[H_ + i] = bihb[i] + bhhb[i];
  }
}

// ---------------------------------------------------------------------------
// GEMM: xp[dir][m][n] = sum_k x16[m][k] * W16[dir][n][k] + bias[dir][n]
// stored into out[m*2048 + dir*1024 + n] (xp lives in d_out; scan updates it
// in place).
// ---------------------------------------------------------------------------
__global__ void __launch_bounds__(256) gemm_xp_kernel(
    const _Float16* __restrict__ A,
    const _Float16* __restrict__ W,
    const float*    __restrict__ bias,
    float*          __restrict__ out)
{
  __shared__ _Float16 alds[128 * 32];
  __shared__ _Float16 blds[128 * 32];

  const int dir = blockIdx.z;
  const int m0  = blockIdx.y * 128;
  const int n0  = blockIdx.x * 128;
  const int tid  = threadIdx.x;
  const int lane = tid & 63;
  const int wv   = tid >> 6;
  const int wm   = wv >> 1, wn = wv & 1;
  const int lrow = lane & 15;
  const int lkg  = lane >> 4;

  const _Float16* Wd = W + (long)dir * H_ * I_;

  floatx4 acc[4][4] = {};

  const int srow = tid >> 1;
  const int sseg = tid & 1;

  for (int kt = 0; kt < 32; ++kt) {
    __syncthreads();
    {
      const _Float16* srcA = A  + (long)(m0 + srow) * I_ + kt * 32 + sseg * 16;
      const _Float16* srcB = Wd + (long)(n0 + srow) * I_ + kt * 32 + sseg * 16;
      half8 a0 = *(const half8*)(srcA);
      half8 a1 = *(const half8*)(srcA + 8);
      half8 b0 = *(const half8*)(srcB);
      half8 b1 = *(const half8*)(srcB + 8);
      const int sw = (srow & 7) << 4;
      const int base = srow * 64 + sseg * 32;
      *(half8*)((char*)alds + ((base     ) ^ sw)) = a0;
      *(half8*)((char*)alds + ((base + 16) ^ sw)) = a1;
      *(half8*)((char*)blds + ((base     ) ^ sw)) = b0;
      *(half8*)((char*)blds + ((base + 16) ^ sw)) = b1;
    }
    __syncthreads();

    half8 af[4], bf[4];
#pragma unroll
    for (int mt = 0; mt < 4; ++mt) {
      int r = wm * 64 + mt * 16 + lrow;
      int byte = (r * 64 + lkg * 16) ^ ((r & 7) << 4);
      af[mt] = *(const half8*)((const char*)alds + byte);
    }
#pragma unroll
    for (int ntt = 0; ntt < 4; ++ntt) {
      int r = wn * 64 + ntt * 16 + lrow;
      int byte = (r * 64 + lkg * 16) ^ ((r & 7) << 4);
      bf[ntt] = *(const half8*)((const char*)blds + byte);
    }
#pragma unroll
    for (int mt = 0; mt < 4; ++mt)
#pragma unroll
      for (int ntt = 0; ntt < 4; ++ntt)
        acc[mt][ntt] = __builtin_amdgcn_mfma_f32_16x16x32_f16(af[mt], bf[ntt], acc[mt][ntt], 0, 0, 0);
  }

#pragma unroll
  for (int mt = 0; mt < 4; ++mt) {
    int mrow = m0 + wm * 64 + mt * 16 + lkg * 4;
#pragma unroll
    for (int ntt = 0; ntt < 4; ++ntt) {
      int n = n0 + wn * 64 + ntt * 16 + lrow;
      float bv = bias[dir * H_ + n];
#pragma unroll
      for (int v = 0; v < 4; ++v) {
        out[(long)(mrow + v) * (2 * H_) + dir * H_ + n] = acc[mt][ntt][v] + bv;
      }
    }
  }
}

// ---------------------------------------------------------------------------
// Recurrent scan, flag-wavefront edition (R6 structure, barrier removed).
// 64 WGs: dir = wg>>5, rb = wg&31 owns rows [rb*32, rb*32+32) of its dir.
// All cross-WG data at agent scope (sc1 -> MALL), proven R4/R6.
// NO global barrier: 128 per-(rb,tile,nt) monotonic epoch flags per dir.
//  - producer wave: h-store -> vmcnt(0) -> lane0 flag := t+2 (plain store,
//    no RMW, no post-store syncthreads).
//  - consumer wave: 32 lanes load their 32 relevant flags, __all(>= t+1),
//    proceed. Autonomous per wave; straggler slack propagates instead of
//    globally synchronizing each step.
// Safety: WG's step-(t+1) h-store (overwrites h[t] buffer) is gated via its
// 4 waves' polls + the redlds __syncthreads on ALL 128 flags >= t+2, which
// implies every WG finished READING h[t]. redlds parity-double-buffered.
// ---------------------------------------------------------------------------
__global__ void __launch_bounds__(256, 1) scan_kernel(
    const float* __restrict__ Whh_f,
    const float* __restrict__ Whh_b,
    float*       __restrict__ out,     // [B][S][2H]; holds xp on entry
    _Float16*    __restrict__ hbuf,    // [2 buf][2 dir][B][H] f16
    unsigned int* __restrict__ flags)  // [2 dir][128]: idx = rb*4 + tile*2 + nt
{
  __shared__ _Float16 wlds[32 * 1024];     // 64 KiB
  __shared__ floatx4  redlds[2 * 4 * 64];  // 8 KiB, parity-double-buffered

  const int w     = blockIdx.x;
  const int dir   = w >> 5;
  const int rb    = w & 31;
  const int rows0 = rb * 32;
  const float* Whh = dir ? Whh_b : Whh_f;
  unsigned int* fl = flags + dir * 128;
  const int tid = threadIdx.x;

  // stage W_hh rows [rows0, rows0+32) as f16, swizzled: byte ^= (row&7)<<4
  for (int idx = tid; idx < 32 * 128; idx += 256) {
    const int r  = idx >> 7;
    const int kg = idx & 127;
    const float* src = Whh + (long)(rows0 + r) * H_ + kg * 8;
    floatx4 v0 = *(const floatx4*)(src);
    floatx4 v1 = *(const floatx4*)(src + 4);
    half8 h = {(_Float16)v0[0], (_Float16)v0[1], (_Float16)v0[2], (_Float16)v0[3],
               (_Float16)v1[0], (_Float16)v1[1], (_Float16)v1[2], (_Float16)v1[3]};
    const int byte = (r * 2048 + kg * 16) ^ ((r & 7) << 4);
    *(half8*)((char*)wlds + byte) = h;
  }

  // wave/lane roles (identical to R6)
  const int lane = tid & 63;
  const int wv   = tid >> 6;
  const int nt   = wv & 1;          // batch half
  const int kh   = wv >> 1;         // K half / owned tile
  const int lrow = lane & 15;
  const int lkg  = lane >> 4;       // 0..3
  const int b_idx = nt * 16 + lrow; // batch
  const int kbase = kh * 512;       // K-half start (halves)
  const int r0    = rows0 + kh * 16 + lkg * 4;  // this lane's 4 output rows
  const int asw   = (lrow & 7) << 4;
  const int abase0 = lrow * 2048 + kbase * 2;        // tile0 row byte base
  const int abase1 = (16 + lrow) * 2048 + kbase * 2; // tile1 row byte base

  // zero-init own h0 tile (one u64/lane = 4 rows x 1 batch), publish flag=1
  {
    u64* pz = (u64*)(hbuf + ((long)(0 * 2 + dir) * B_ + b_idx) * H_ + r0);
    __hip_atomic_store(pz, (u64)0, __ATOMIC_RELAXED, __HIP_MEMORY_SCOPE_AGENT);
  }
  asm volatile("s_waitcnt vmcnt(0)" ::: "memory");
  if (lane == 0)
    __hip_atomic_store(&fl[rb * 4 + kh * 2 + nt], 1u, __ATOMIC_RELAXED, __HIP_MEMORY_SCOPE_AGENT);
  __syncthreads();  // W LDS visible to all waves

  // this wave's 32 poll targets: prods kh*16..+16, both tiles, own nt
  const int pl = lane & 31;
  const unsigned int* fpoll = fl + (kh * 16 + (pl >> 1)) * 4 + (pl & 1) * 2 + nt;

  // 1-step-ahead xp prefetch (own cells only)
  long o_nxt = ((long)b_idx * S_ + (dir ? (S_ - 1) : 0)) * (2 * H_) + dir * H_ + r0;
  floatx4 xp_n = *(const floatx4*)(out + o_nxt);

#pragma unroll 1
  for (int t = 0; t < S_; ++t) {
    const int p = t & 1;

    // ---- autonomous flag poll: h[t] published by my 16 producers? ----
    {
      const unsigned int tgt = (unsigned)(t + 1);
      while (true) {
        unsigned int v = __hip_atomic_load(fpoll, __ATOMIC_RELAXED, __HIP_MEMORY_SCOPE_AGENT);
        if (__all((int)(v >= tgt))) break;
      }
    }

    // ---- batched h loads: 16 x dwordx4 sc1, one exposed MALL latency ----
    const _Float16* hp = hbuf + ((long)(p * 2 + dir) * B_ + b_idx) * H_ + kbase + lkg * 8;
    half8 hr[16];
#pragma unroll
    for (int kt = 0; kt < 16; ++kt)
      asm volatile("global_load_dwordx4 %0, %1, off offset:%2 sc1"
                   : "=v"(hr[kt]) : "v"(hp), "i"(kt * 64) : "memory");
    asm volatile("s_waitcnt vmcnt(0)" ::: "memory");
    __builtin_amdgcn_sched_barrier(0);

    // ---- MFMA: both row tiles, this K-half ----
    floatx4 a0 = {}, a1 = {};
#pragma unroll
    for (int kt = 0; kt < 16; ++kt) {
      const int koff = kt * 64 + lkg * 16;
      half8 wa = *(const half8*)((const char*)wlds + ((abase0 + koff) ^ asw));
      half8 wb = *(const half8*)((const char*)wlds + ((abase1 + koff) ^ asw));
      a0 = __builtin_amdgcn_mfma_f32_16x16x32_f16(wa, hr[kt], a0, 0, 0, 0);
      a1 = __builtin_amdgcn_mfma_f32_16x16x32_f16(wb, hr[kt], a1, 0, 0, 0);
    }

    // ---- kh partial exchange (parity-buffered): ship non-owned tile ----
    redlds[(p * 4 + (1 - kh) * 2 + nt) * 64 + lane] = kh ? a0 : a1;
    __syncthreads();
    floatx4 tot = (kh ? a1 : a0) + redlds[(p * 4 + kh * 2 + nt) * 64 + lane];

    const long o = o_nxt;
    const floatx4 xpv = xp_n;
    floatx4 hv;
#pragma unroll
    for (int v = 0; v < 4; ++v) {
      float z = tot[v] + xpv[v];
      hv[v] = 1.f - 2.f / (__expf(2.f * z) + 1.f);   // tanh(z)
    }
    *(floatx4*)(out + o) = hv;

    if (t + 1 < S_) {
      // h store (sc1) -> own-wave ack -> publish epoch flag (no RMW)
      union { half4v h; u64 u; } hh;
      hh.h = half4v{(_Float16)hv[0], (_Float16)hv[1], (_Float16)hv[2], (_Float16)hv[3]};
      u64* dst = (u64*)(hbuf + ((long)((1 - p) * 2 + dir) * B_ + b_idx) * H_ + r0);
      __hip_atomic_store(dst, hh.u, __ATOMIC_RELAXED, __HIP_MEMORY_SCOPE_AGENT);
      asm volatile("s_waitcnt vmcnt(0)" ::: "memory");
      if (lane == 0)
        __hip_atomic_store(&fl[rb * 4 + kh * 2 + nt], (unsigned)(t + 2),
                           __ATOMIC_RELAXED, __HIP_MEMORY_SCOPE_AGENT);
      // xp prefetch for t+1: latency overlaps next poll
      const int sidx1 = dir ? (S_ - 2 - t) : (t + 1);
      o_nxt = ((long)b_idx * S_ + sidx1) * (2 * H_) + dir * H_ + r0;
      xp_n = *(const floatx4*)(out + o_nxt);
    }
  }
}

// ---------------------------------------------------------------------------
extern "C" void kernel_launch(void* const* d_in, const int* in_sizes, int n_in,
                              void* d_out, int out_size, void* d_ws, size_t ws_size,
                              hipStream_t stream) {
  const float* x    = (const float*)d_in[0];
  const float* Wihf = (const float*)d_in[1];
  const float* Whhf = (const float*)d_in[2];
  const float* bihf = (const float*)d_in[3];
  const float* bhhf = (const float*)d_in[4];
  const float* Wihb = (const float*)d_in[5];
  const float* Whhb = (const float*)d_in[6];
  const float* bihb = (const float*)d_in[7];
  const float* bhhb = (const float*)d_in[8];
  float* out = (float*)d_out;

  // workspace layout
  char* ws = (char*)d_ws;
  _Float16*     x16   = (_Float16*)ws;                          // 32 MiB
  _Float16*     w16   = (_Float16*)(ws + 33554432u);            // 4 MiB
  float*        bias  = (float*)   (ws + 33554432u + 4194304u); // 8 KiB
  _Float16*     hbuf  = (_Float16*)(ws + 37756928u);            // 256 KiB
  unsigned int* flags = (unsigned int*)(ws + 38019072u);        // 1 KiB

  cvt_f32_f16<<<4096, 256, 0, stream>>>(x, x16, (long)M_TOT * I_);
  cvt_f32_f16<<<1024, 256, 0, stream>>>(Wihf, w16, (long)H_ * I_);
  cvt_f32_f16<<<1024, 256, 0, stream>>>(Wihb, w16 + (long)H_ * I_, (long)H_ * I_);
  bias_sum_kernel<<<4, 256, 0, stream>>>(bihf, bhhf, bihb, bhhb, bias, flags);

  dim3 g(H_ / 128, M_TOT / 128, 2);
  gemm_xp_kernel<<<g, 256, 0, stream>>>(x16, w16, bias, out);

  void* args[] = {(void*)&Whhf, (void*)&Whhb, (void*)&out, (void*)&hbuf, (void*)&flags};
  (void)hipLaunchCooperativeKernel((void*)scan_kernel, dim3(64), dim3(256),
                                   args, 0, stream);
}

// Round 9
// 2253.784 us; speedup vs baseline: 1.5138x; 1.3801x over previous
//
#include <hip/hip_runtime.h>

typedef _Float16 half8  __attribute__((ext_vector_type(8)));
typedef _Float16 half4v __attribute__((ext_vector_type(4)));
typedef float    floatx4 __attribute__((ext_vector_type(4)));
typedef unsigned long long u64;

#define B_ 32
#define S_ 512
#define I_ 1024
#define H_ 1024
#define M_TOT (B_ * S_)   // 16384

// ---------------------------------------------------------------------------
// fp32 -> fp16 conversion (vectorized, grid-stride), n multiple of 4
// ---------------------------------------------------------------------------
__global__ void cvt_f32_f16(const float* __restrict__ src, _Float16* __restrict__ dst, long n) {
  long i = ((long)blockIdx.x * blockDim.x + threadIdx.x) * 4;
  const long stride = (long)gridDim.x * blockDim.x * 4;
  for (; i < n; i += stride) {
    floatx4 v = *(const floatx4*)(src + i);
    half4v h = {(_Float16)v[0], (_Float16)v[1], (_Float16)v[2], (_Float16)v[3]};
    *(half4v*)(dst + i) = h;
  }
}

__global__ void bias_sum_kernel(const float* __restrict__ bihf, const float* __restrict__ bhhf,
                                const float* __restrict__ bihb, const float* __restrict__ bhhb,
                                float* __restrict__ bias, unsigned int* __restrict__ ctrs) {
  int i = blockIdx.x * blockDim.x + threadIdx.x;
  if (i < 1024) {  // zero the 4 KB counter region each launch (replay-safe)
    __hip_atomic_store(ctrs + i, 0u, __ATOMIC_RELAXED, __HIP_MEMORY_SCOPE_AGENT);
  }
  if (i < H_) {
    bias[i]      = bihf[i] + bhhf[i];
    bias[H_ + i] = bihb[i] + bhhb[i];
  }
}

// ---------------------------------------------------------------------------
// GEMM: xp[dir][m][n] = sum_k x16[m][k] * W16[dir][n][k] + bias[dir][n]
// stored into out[m*2048 + dir*1024 + n] (xp lives in d_out; scan updates it
// in place).
// ---------------------------------------------------------------------------
__global__ void __launch_bounds__(256) gemm_xp_kernel(
    const _Float16* __restrict__ A,
    const _Float16* __restrict__ W,
    const float*    __restrict__ bias,
    float*          __restrict__ out)
{
  __shared__ _Float16 alds[128 * 32];
  __shared__ _Float16 blds[128 * 32];

  const int dir = blockIdx.z;
  const int m0  = blockIdx.y * 128;
  const int n0  = blockIdx.x * 128;
  const int tid  = threadIdx.x;
  const int lane = tid & 63;
  const int wv   = tid >> 6;
  const int wm   = wv >> 1, wn = wv & 1;
  const int lrow = lane & 15;
  const int lkg  = lane >> 4;

  const _Float16* Wd = W + (long)dir * H_ * I_;

  floatx4 acc[4][4] = {};

  const int srow = tid >> 1;
  const int sseg = tid & 1;

  for (int kt = 0; kt < 32; ++kt) {
    __syncthreads();
    {
      const _Float16* srcA = A  + (long)(m0 + srow) * I_ + kt * 32 + sseg * 16;
      const _Float16* srcB = Wd + (long)(n0 + srow) * I_ + kt * 32 + sseg * 16;
      half8 a0 = *(const half8*)(srcA);
      half8 a1 = *(const half8*)(srcA + 8);
      half8 b0 = *(const half8*)(srcB);
      half8 b1 = *(const half8*)(srcB + 8);
      const int sw = (srow & 7) << 4;
      const int base = srow * 64 + sseg * 32;
      *(half8*)((char*)alds + ((base     ) ^ sw)) = a0;
      *(half8*)((char*)alds + ((base + 16) ^ sw)) = a1;
      *(half8*)((char*)blds + ((base     ) ^ sw)) = b0;
      *(half8*)((char*)blds + ((base + 16) ^ sw)) = b1;
    }
    __syncthreads();

    half8 af[4], bf[4];
#pragma unroll
    for (int mt = 0; mt < 4; ++mt) {
      int r = wm * 64 + mt * 16 + lrow;
      int byte = (r * 64 + lkg * 16) ^ ((r & 7) << 4);
      af[mt] = *(const half8*)((const char*)alds + byte);
    }
#pragma unroll
    for (int ntt = 0; ntt < 4; ++ntt) {
      int r = wn * 64 + ntt * 16 + lrow;
      int byte = (r * 64 + lkg * 16) ^ ((r & 7) << 4);
      bf[ntt] = *(const half8*)((const char*)blds + byte);
    }
#pragma unroll
    for (int mt = 0; mt < 4; ++mt)
#pragma unroll
      for (int ntt = 0; ntt < 4; ++ntt)
        acc[mt][ntt] = __builtin_amdgcn_mfma_f32_16x16x32_f16(af[mt], bf[ntt], acc[mt][ntt], 0, 0, 0);
  }

#pragma unroll
  for (int mt = 0; mt < 4; ++mt) {
    int mrow = m0 + wm * 64 + mt * 16 + lkg * 4;
#pragma unroll
    for (int ntt = 0; ntt < 4; ++ntt) {
      int n = n0 + wn * 64 + ntt * 16 + lrow;
      float bv = bias[dir * H_ + n];
#pragma unroll
      for (int v = 0; v < 4; ++v) {
        out[(long)(mrow + v) * (2 * H_) + dir * H_ + n] = acc[mt][ntt][v] + bv;
      }
    }
  }
}

// ---------------------------------------------------------------------------
// Recurrent scan, per-wave sub-counter edition (R6 data path, new sync).
// 64 WGs: dir = wg>>5, rb = wg&31 owns rows [rb*32, rb*32+32).
// 32 monotonic sub-counters, 128 B apart: key (dir, nt, kh-class, rb-octet),
// idx = ((dir*2+nt)*2 + kh)*4 + (rb>>3), word offset idx*32.
//  - signal: each WAVE, right after its own h-store vmcnt(0) ack, lane0 adds
//    1 to its counter. No intra-WG join; adds only 8-deep per line, 8 lines
//    in parallel.
//  - poll: each wave autonomously polls the 8 counters of its (dir,nt) block
//    (lanes 0-7, one vector load = one MALL trip) for >= 8*(t+1).
// Safety: the poll covers both the wave's producers AND all reader-waves
// (class (khP,nt), every octet) of the h[t-1] tile it overwrites at step t.
// Only ONE __syncthreads/step (parity-double-buffered redlds exchange),
// unconditional -> barrier instances aligned. out-store + xp prefetch issued
// AFTER the signal so their acks overlap the next poll.
// ---------------------------------------------------------------------------
__global__ void __launch_bounds__(256, 1) scan_kernel(
    const float* __restrict__ Whh_f,
    const float* __restrict__ Whh_b,
    float*       __restrict__ out,     // [B][S][2H]; holds xp on entry
    _Float16*    __restrict__ hbuf,    // [2 buf][2 dir][B][H] f16
    unsigned int* __restrict__ ctrs)   // 32 sub-counters, 128 B apart
{
  __shared__ _Float16 wlds[32 * 1024];     // 64 KiB
  __shared__ floatx4  redlds[2 * 4 * 64];  // 8 KiB, parity-double-buffered

  const int w     = blockIdx.x;
  const int dir   = w >> 5;
  const int rb    = w & 31;
  const int rows0 = rb * 32;
  const float* Whh = dir ? Whh_b : Whh_f;
  const int tid = threadIdx.x;

  // stage W_hh rows [rows0, rows0+32) as f16, swizzled: byte ^= (row&7)<<4
  for (int idx = tid; idx < 32 * 128; idx += 256) {
    const int r  = idx >> 7;
    const int kg = idx & 127;
    const float* src = Whh + (long)(rows0 + r) * H_ + kg * 8;
    floatx4 v0 = *(const floatx4*)(src);
    floatx4 v1 = *(const floatx4*)(src + 4);
    half8 h = {(_Float16)v0[0], (_Float16)v0[1], (_Float16)v0[2], (_Float16)v0[3],
               (_Float16)v1[0], (_Float16)v1[1], (_Float16)v1[2], (_Float16)v1[3]};
    const int byte = (r * 2048 + kg * 16) ^ ((r & 7) << 4);
    *(half8*)((char*)wlds + byte) = h;
  }

  // wave/lane roles
  const int lane = tid & 63;
  const int wv   = tid >> 6;
  const int nt   = wv & 1;          // batch half
  const int kh   = wv >> 1;         // K half / owned row tile
  const int lrow = lane & 15;
  const int lkg  = lane >> 4;       // 0..3
  const int b_idx = nt * 16 + lrow; // batch
  const int kbase = kh * 512;       // K-half start (halves)
  const int r0    = rows0 + kh * 16 + lkg * 4;  // this lane's 4 output rows
  const int asw   = (lrow & 7) << 4;
  const int abase0 = lrow * 2048 + kbase * 2;        // tile0 row byte base
  const int abase1 = (16 + lrow) * 2048 + kbase * 2; // tile1 row byte base

  unsigned int* sig  = ctrs + (((dir * 2 + nt) * 2 + kh) * 4 + (rb >> 3)) * 32;
  unsigned int* pbas = ctrs + ((dir * 2 + nt) * 8) * 32;

  // zero-init own h0 tile (one u64/lane = 4 rows x 1 batch)
  {
    u64* pz = (u64*)(hbuf + ((long)(0 * 2 + dir) * B_ + b_idx) * H_ + r0);
    __hip_atomic_store(pz, (u64)0, __ATOMIC_RELAXED, __HIP_MEMORY_SCOPE_AGENT);
  }
  asm volatile("s_waitcnt vmcnt(0)" ::: "memory");
  __syncthreads();  // W LDS visible to all waves (1 unconditional instance)
  if (lane == 0)
    __hip_atomic_fetch_add(sig, 1u, __ATOMIC_RELAXED, __HIP_MEMORY_SCOPE_AGENT);

  // 1-step-ahead xp prefetch (own cells only)
  long o_nxt = ((long)b_idx * S_ + (dir ? (S_ - 1) : 0)) * (2 * H_) + dir * H_ + r0;
  floatx4 xp_n = *(const floatx4*)(out + o_nxt);

#pragma unroll 1
  for (int t = 0; t < S_; ++t) {
    const int p = t & 1;

    // ---- autonomous poll: 8 sub-counters of my (dir,nt), one trip/iter ----
    {
      const unsigned int tgt = 8u * (unsigned)(t + 1);
      for (;;) {
        unsigned int v = tgt;
        if (lane < 8)
          v = __hip_atomic_load(pbas + lane * 32, __ATOMIC_RELAXED, __HIP_MEMORY_SCOPE_AGENT);
        if (__all((int)(v >= tgt))) break;
        __builtin_amdgcn_s_sleep(1);
      }
    }

    // ---- batched h loads: 16 x dwordx4 sc1, one exposed MALL latency ----
    const _Float16* hp = hbuf + ((long)(p * 2 + dir) * B_ + b_idx) * H_ + kbase + lkg * 8;
    half8 hr[16];
#pragma unroll
    for (int kt = 0; kt < 16; ++kt)
      asm volatile("global_load_dwordx4 %0, %1, off offset:%2 sc1"
                   : "=v"(hr[kt]) : "v"(hp), "i"(kt * 64) : "memory");
    asm volatile("s_waitcnt vmcnt(0)" ::: "memory");
    __builtin_amdgcn_sched_barrier(0);

    // ---- MFMA: both row tiles, this K-half ----
    floatx4 a0 = {}, a1 = {};
#pragma unroll
    for (int kt = 0; kt < 16; ++kt) {
      const int koff = kt * 64 + lkg * 16;
      half8 wa = *(const half8*)((const char*)wlds + ((abase0 + koff) ^ asw));
      half8 wb = *(const half8*)((const char*)wlds + ((abase1 + koff) ^ asw));
      a0 = __builtin_amdgcn_mfma_f32_16x16x32_f16(wa, hr[kt], a0, 0, 0, 0);
      a1 = __builtin_amdgcn_mfma_f32_16x16x32_f16(wb, hr[kt], a1, 0, 0, 0);
    }

    // ---- kh partial exchange (parity-buffered), ONE syncthreads/step ----
    redlds[((p * 2 + (1 - kh)) * 2 + nt) * 64 + lane] = kh ? a0 : a1;
    __syncthreads();
    floatx4 tot = (kh ? a1 : a0) + redlds[((p * 2 + kh) * 2 + nt) * 64 + lane];

    const long o = o_nxt;
    const floatx4 xpv = xp_n;
    floatx4 hv;
#pragma unroll
    for (int v = 0; v < 4; ++v) {
      float z = tot[v] + xpv[v];
      hv[v] = 1.f - 2.f / (__expf(2.f * z) + 1.f);   // tanh(z)
    }

    if (t + 1 < S_) {
      // h store (sc1) -> own-wave ack -> per-wave signal (no syncthreads)
      union { half4v h; u64 u; } hh;
      hh.h = half4v{(_Float16)hv[0], (_Float16)hv[1], (_Float16)hv[2], (_Float16)hv[3]};
      u64* dst = (u64*)(hbuf + ((long)((1 - p) * 2 + dir) * B_ + b_idx) * H_ + r0);
      __hip_atomic_store(dst, hh.u, __ATOMIC_RELAXED, __HIP_MEMORY_SCOPE_AGENT);
      asm volatile("s_waitcnt vmcnt(0)" ::: "memory");
      if (lane == 0)
        __hip_atomic_fetch_add(sig, 1u, __ATOMIC_RELAXED, __HIP_MEMORY_SCOPE_AGENT);
    }

    // out store + next xp prefetch AFTER the signal: acks overlap next poll
    *(floatx4*)(out + o) = hv;
    if (t + 1 < S_) {
      const int sidx1 = dir ? (S_ - 2 - t) : (t + 1);
      o_nxt = ((long)b_idx * S_ + sidx1) * (2 * H_) + dir * H_ + r0;
      xp_n = *(const floatx4*)(out + o_nxt);
    }
  }
}

// ---------------------------------------------------------------------------
extern "C" void kernel_launch(void* const* d_in, const int* in_sizes, int n_in,
                              void* d_out, int out_size, void* d_ws, size_t ws_size,
                              hipStream_t stream) {
  const float* x    = (const float*)d_in[0];
  const float* Wihf = (const float*)d_in[1];
  const float* Whhf = (const float*)d_in[2];
  const float* bihf = (const float*)d_in[3];
  const float* bhhf = (const float*)d_in[4];
  const float* Wihb = (const float*)d_in[5];
  const float* Whhb = (const float*)d_in[6];
  const float* bihb = (const float*)d_in[7];
  const float* bhhb = (const float*)d_in[8];
  float* out = (float*)d_out;

  // workspace layout
  char* ws = (char*)d_ws;
  _Float16*     x16  = (_Float16*)ws;                          // 32 MiB
  _Float16*     w16  = (_Float16*)(ws + 33554432u);            // 4 MiB
  float*        bias = (float*)   (ws + 33554432u + 4194304u); // 8 KiB
  _Float16*     hbuf = (_Float16*)(ws + 37756928u);            // 256 KiB
  unsigned int* ctrs = (unsigned int*)(ws + 38019072u);        // 4 KiB

  cvt_f32_f16<<<4096, 256, 0, stream>>>(x, x16, (long)M_TOT * I_);
  cvt_f32_f16<<<1024, 256, 0, stream>>>(Wihf, w16, (long)H_ * I_);
  cvt_f32_f16<<<1024, 256, 0, stream>>>(Wihb, w16 + (long)H_ * I_, (long)H_ * I_);
  bias_sum_kernel<<<4, 256, 0, stream>>>(bihf, bhhf, bihb, bhhb, bias, ctrs);

  dim3 g(H_ / 128, M_TOT / 128, 2);
  gemm_xp_kernel<<<g, 256, 0, stream>>>(x16, w16, bias, out);

  void* args[] = {(void*)&Whhf, (void*)&Whhb, (void*)&out, (void*)&hbuf, (void*)&ctrs};
  (void)hipLaunchCooperativeKernel((void*)scan_kernel, dim3(64), dim3(256),
                                   args, 0, stream);
}